// Round 3
// baseline (13521.104 us; speedup 1.0000x reference)
//
#include <hip/hip_runtime.h>
#include <math.h>

#define DIM 128
#define N_ENT 100000
#define N_REL 500
#define N_EDGE 3200000
#define LN_EPS 1e-6f
#define ALPHA 0.2f

// ---------- helpers ----------

__device__ __forceinline__ float wred(float v) {
#pragma unroll
  for (int o = 32; o > 0; o >>= 1) v += __shfl_xor(v, o, 64);
  return v;
}

// One wave computes row-vector (q) times 128x128 row-major matrix in LDS.
// Lane holds q elements (2*lane, 2*lane+1); returns output cols (2*lane, 2*lane+1).
__device__ __forceinline__ float2 wave_gemv(float q0, float q1, const float* __restrict__ Wl, int lane) {
  float ax = 0.f, ay = 0.f;
#pragma unroll
  for (int kk = 0; kk < 64; ++kk) {
    float qa = __shfl(q0, kk, 64);   // q[2kk]
    float qb = __shfl(q1, kk, 64);   // q[2kk+1]
    float2 w0 = *(const float2*)&Wl[(2 * kk) * DIM + 2 * lane];
    float2 w1 = *(const float2*)&Wl[(2 * kk + 1) * DIM + 2 * lane];
    ax = fmaf(qa, w0.x, ax); ay = fmaf(qa, w0.y, ay);
    ax = fmaf(qb, w1.x, ax); ay = fmaf(qb, w1.y, ay);
  }
  return make_float2(ax, ay);
}

__device__ __forceinline__ void stageW(float* Wl, const float* __restrict__ W) {
  for (int i = threadIdx.x; i < DIM * DIM / 4; i += blockDim.x)
    ((float4*)Wl)[i] = ((const float4*)W)[i];
  __syncthreads();
}

// LN of (x0,x1) across wave (128 elems); returns normalized pre-affine values
__device__ __forceinline__ void wave_ln(float x0, float x1, float& d0s, float& d1s) {
  float m = wred(x0 + x1) * (1.f / DIM);
  float d0 = x0 - m, d1 = x1 - m;
  float var = wred(d0 * d0 + d1 * d1) * (1.f / DIM);
  float rs = rsqrtf(var + LN_EPS);
  d0s = d0 * rs; d1s = d1 * rs;
}

// ---------- precompute: column-structure sums for local-attn sum1/sum2 ----------
// sum(q@W1+b1, axis=1) == q . rowsum_j(W1[k][j]) + sum(b1)
__global__ void k_colsum(const float* __restrict__ W1, const float* __restrict__ b1,
                         const float* __restrict__ W2, const float* __restrict__ b2,
                         float* __restrict__ w1s, float* __restrict__ w2s, float* __restrict__ cst) {
  int t = threadIdx.x;  // 128 threads
  float s1 = 0.f, s2 = 0.f;
  for (int j = 0; j < DIM; ++j) { s1 += W1[t * DIM + j]; s2 += W2[t * DIM + j]; }
  w1s[t] = s1; w2s[t] = s2;
  if (t == 0) {
    float a = 0.f, c = 0.f;
    for (int j = 0; j < DIM; ++j) { a += b1[j]; c += b2[j]; }
    cst[0] = a; cst[1] = c;
  }
}

// ---------- K1: local-attn row pass: LN -> value GEMV, sum1/sum2 dots ----------
__global__ __launch_bounds__(256) void k_la_rows(
    const float* __restrict__ ent, const float* __restrict__ g, const float* __restrict__ b,
    const float* __restrict__ W, const float* __restrict__ wb,
    const float* __restrict__ w1s, const float* __restrict__ w2s, const float* __restrict__ cst,
    float* __restrict__ value, float* __restrict__ sum1, float* __restrict__ sum2,
    int n, int rowsPerBlock) {
  __shared__ float Wl[DIM * DIM];
  stageW(Wl, W);
  int lane = threadIdx.x & 63, wid = threadIdx.x >> 6;
  float2 gv  = *(const float2*)&g[2 * lane];
  float2 bv  = *(const float2*)&b[2 * lane];
  float2 wbv = *(const float2*)&wb[2 * lane];
  float2 w1v = *(const float2*)&w1s[2 * lane];
  float2 w2v = *(const float2*)&w2s[2 * lane];
  float b1s = cst[0], b2s = cst[1];
  int r0 = blockIdx.x * rowsPerBlock;
  int r1 = min(n, r0 + rowsPerBlock);
  for (int r = r0 + wid; r < r1; r += 4) {
    float2 x = *(const float2*)&ent[(size_t)r * DIM + 2 * lane];
    float d0, d1;
    wave_ln(x.x, x.y, d0, d1);
    float q0 = fmaf(d0, gv.x, bv.x);
    float q1 = fmaf(d1, gv.y, bv.y);
    float p1 = wred(q0 * w1v.x + q1 * w1v.y);
    float p2 = wred(q0 * w2v.x + q1 * w2v.y);
    if (lane == 0) { sum1[r] = tanhf(p1 + b1s); sum2[r] = tanhf(p2 + b2s); }
    float2 acc = wave_gemv(q0, q1, Wl, lane);
    acc.x += wbv.x; acc.y += wbv.y;
    *(float2*)&value[(size_t)r * DIM + 2 * lane] = acc;
  }
}

// ---------- edge pass (shared by local and er): softmax-numerator accumulate ----------
__global__ __launch_bounds__(256) void k_edge(
    const int* __restrict__ src, const int* __restrict__ dst,
    const float* __restrict__ s1, const float* __restrict__ s2,
    const float* __restrict__ rows, float* __restrict__ acc, float* __restrict__ denom, int E) {
  int gid = blockIdx.x * 256 + threadIdx.x;
  int group = gid >> 5, sub = gid & 31;
  int ngroups = (gridDim.x * 256) >> 5;
  for (int e = group; e < E; e += ngroups) {
    int s = src[e], d = dst[e];
    float x = s1[s] + s2[d];
    x = x >= 0.f ? x : ALPHA * x;
    float w = expf(x);  // logits bounded in (-0.4, 2]: softmax without max-sub is exact
    float4 v = *(const float4*)&rows[(size_t)d * DIM + sub * 4];
    float* ap = &acc[(size_t)s * DIM + sub * 4];
    unsafeAtomicAdd(ap + 0, w * v.x);
    unsafeAtomicAdd(ap + 1, w * v.y);
    unsafeAtomicAdd(ap + 2, w * v.z);
    unsafeAtomicAdd(ap + 3, w * v.w);
    if (sub == 0) unsafeAtomicAdd(&denom[s], w);
  }
}

// ---------- K3: local post: divide, LN(ln2) -> e_out (in place), er quadform sum1 ----------
__global__ __launch_bounds__(256) void k_la_post(
    float* __restrict__ buf, const float* __restrict__ denom,
    const float* __restrict__ g, const float* __restrict__ b,
    const float* __restrict__ W1, const float* __restrict__ w1b,
    float* __restrict__ sum1er, int n, int rowsPerBlock) {
  __shared__ float Wl[DIM * DIM];
  stageW(Wl, W1);
  int lane = threadIdx.x & 63, wid = threadIdx.x >> 6;
  float2 gv  = *(const float2*)&g[2 * lane];
  float2 bv  = *(const float2*)&b[2 * lane];
  float2 b1v = *(const float2*)&w1b[2 * lane];
  int r0 = blockIdx.x * rowsPerBlock, r1 = min(n, r0 + rowsPerBlock);
  for (int r = r0 + wid; r < r1; r += 4) {
    float2 a = *(const float2*)&buf[(size_t)r * DIM + 2 * lane];
    float dn = denom[r];
    float inv = dn > 0.f ? 1.f / dn : 0.f;
    float d0, d1;
    wave_ln(a.x * inv, a.y * inv, d0, d1);
    float e0 = fmaf(d0, gv.x, bv.x);
    float e1 = fmaf(d1, gv.y, bv.y);
    *(float2*)&buf[(size_t)r * DIM + 2 * lane] = make_float2(e0, e1);
    // sum1_er = tanh(e^T W1 e + b1 . e)
    float2 y = wave_gemv(e0, e1, Wl, lane);
    float p = wred(y.x * e0 + y.y * e1 + b1v.x * e0 + b1v.y * e1);
    if (lane == 0) sum1er[r] = tanhf(p);
  }
}

// ---------- K4a: rel rows: LN(ea_ln1) -> dense GEMV ----------
__global__ __launch_bounds__(256) void k_rel_dense(
    const float* __restrict__ rel, const float* __restrict__ g, const float* __restrict__ b,
    const float* __restrict__ W, const float* __restrict__ wb,
    float* __restrict__ dense, int n, int rowsPerBlock) {
  __shared__ float Wl[DIM * DIM];
  stageW(Wl, W);
  int lane = threadIdx.x & 63, wid = threadIdx.x >> 6;
  float2 gv  = *(const float2*)&g[2 * lane];
  float2 bv  = *(const float2*)&b[2 * lane];
  float2 wbv = *(const float2*)&wb[2 * lane];
  int r0 = blockIdx.x * rowsPerBlock, r1 = min(n, r0 + rowsPerBlock);
  for (int r = r0 + wid; r < r1; r += 4) {
    float2 x = *(const float2*)&rel[(size_t)r * DIM + 2 * lane];
    float d0, d1;
    wave_ln(x.x, x.y, d0, d1);
    float e0 = fmaf(d0, gv.x, bv.x);
    float e1 = fmaf(d1, gv.y, bv.y);
    float2 acc = wave_gemv(e0, e1, Wl, lane);
    acc.x += wbv.x; acc.y += wbv.y;
    *(float2*)&dense[(size_t)r * DIM + 2 * lane] = acc;
  }
}

// ---------- K4b: rel rows: LN(ea_ln1) -> quadform sum2_er ----------
__global__ __launch_bounds__(256) void k_rel_quad(
    const float* __restrict__ rel, const float* __restrict__ g, const float* __restrict__ b,
    const float* __restrict__ W2, const float* __restrict__ w2b,
    float* __restrict__ sum2er, int n, int rowsPerBlock) {
  __shared__ float Wl[DIM * DIM];
  stageW(Wl, W2);
  int lane = threadIdx.x & 63, wid = threadIdx.x >> 6;
  float2 gv  = *(const float2*)&g[2 * lane];
  float2 bv  = *(const float2*)&b[2 * lane];
  float2 b2v = *(const float2*)&w2b[2 * lane];
  int r0 = blockIdx.x * rowsPerBlock, r1 = min(n, r0 + rowsPerBlock);
  for (int r = r0 + wid; r < r1; r += 4) {
    float2 x = *(const float2*)&rel[(size_t)r * DIM + 2 * lane];
    float d0, d1;
    wave_ln(x.x, x.y, d0, d1);
    float e0 = fmaf(d0, gv.x, bv.x);
    float e1 = fmaf(d1, gv.y, bv.y);
    float2 y = wave_gemv(e0, e1, Wl, lane);
    float p = wred(y.x * e0 + y.y * e1 + b2v.x * e0 + b2v.y * e1);
    if (lane == 0) sum2er[r] = tanhf(p);
  }
}

// ---------- K6: final: er LN, d1 GEMV, combine with e_out ----------
// eout may alias out (in-place safe: each thread reads its element before writing it)
__global__ __launch_bounds__(256) void k_final(
    const float* __restrict__ acc2, const float* __restrict__ denom2,
    const float* eout,
    const float* __restrict__ g, const float* __restrict__ b,
    const float* __restrict__ d1W, const float* __restrict__ d1b,
    float* out, int n, int rowsPerBlock) {
  __shared__ float Wl[DIM * DIM];
  stageW(Wl, d1W);
  int lane = threadIdx.x & 63, wid = threadIdx.x >> 6;
  float2 gv  = *(const float2*)&g[2 * lane];
  float2 bv  = *(const float2*)&b[2 * lane];
  float2 dbv = *(const float2*)&d1b[2 * lane];
  int r0 = blockIdx.x * rowsPerBlock, r1 = min(n, r0 + rowsPerBlock);
  for (int r = r0 + wid; r < r1; r += 4) {
    float2 a = *(const float2*)&acc2[(size_t)r * DIM + 2 * lane];
    float dn = denom2[r];
    float inv = dn > 0.f ? 1.f / dn : 0.f;
    float d0, d1;
    wave_ln(a.x * inv, a.y * inv, d0, d1);
    float er0 = fmaf(d0, gv.x, bv.x);
    float er1 = fmaf(d1, gv.y, bv.y);
    float2 y = wave_gemv(er0, er1, Wl, lane);
    float2 e = *(const float2*)&eout[(size_t)r * DIM + 2 * lane];
    float2 o;
    o.x = e.x + 0.6f * (y.x + dbv.x);
    o.y = e.y + 0.6f * (y.y + dbv.y);
    *(float2*)&out[(size_t)r * DIM + 2 * lane] = o;
  }
}

extern "C" void kernel_launch(void* const* d_in, const int* in_sizes, int n_in,
                              void* d_out, int out_size, void* d_ws, size_t ws_size,
                              hipStream_t stream) {
  const float* ent      = (const float*)d_in[0];
  const float* rel      = (const float*)d_in[1];
  const int*   esrc     = (const int*)d_in[2];
  const int*   edst     = (const int*)d_in[3];
  const int*   rsrc     = (const int*)d_in[4];
  const int*   rdst     = (const int*)d_in[5];
  const float* la_ln1_g = (const float*)d_in[6];
  const float* la_ln1_b = (const float*)d_in[7];
  const float* la_w_W   = (const float*)d_in[8];
  const float* la_w_b   = (const float*)d_in[9];
  const float* la_w1_W  = (const float*)d_in[10];
  const float* la_w1_b  = (const float*)d_in[11];
  const float* la_w2_W  = (const float*)d_in[12];
  const float* la_w2_b  = (const float*)d_in[13];
  const float* la_ln2_g = (const float*)d_in[14];
  const float* la_ln2_b = (const float*)d_in[15];
  const float* ea_ln1_g = (const float*)d_in[16];
  const float* ea_ln1_b = (const float*)d_in[17];
  const float* ea_w_W   = (const float*)d_in[18];
  const float* ea_w_b   = (const float*)d_in[19];
  const float* ea_w1_W  = (const float*)d_in[20];
  const float* ea_w1_b  = (const float*)d_in[21];
  const float* ea_w2_W  = (const float*)d_in[22];
  const float* ea_w2_b  = (const float*)d_in[23];
  const float* ea_ln2_g = (const float*)d_in[24];
  const float* ea_ln2_b = (const float*)d_in[25];
  const float* d1_W     = (const float*)d_in[26];
  const float* d1_b     = (const float*)d_in[27];
  float* out = (float*)d_out;

  // e_out lives in d_out (atomically accumulated, LN'd in place, then combined in place).
  // ws layout (floats); total ~13.4M floats (~54 MB)
  float* f      = (float*)d_ws;
  float* bufA   = f;                  // value (local), then er acc2
  float* denom  = f + 12800000;       // [N]
  float* denom2 = f + 12900000;       // [N]
  float* sum1la = f + 13000000;       // [N]
  float* sum2la = f + 13100000;       // [N]
  float* sum1er = f + 13200000;       // [N]
  float* sum2er = f + 13300000;       // [R]
  float* dense  = f + 13301000;       // [R*128]
  float* w1s    = f + 13365000;       // [128]
  float* w2s    = f + 13365128;       // [128]
  float* cst    = f + 13365256;       // [2]
  float* eout   = out;                // [N*128], doubles as local-attn accumulator

  hipMemsetAsync(denom, 0, 2 * N_ENT * sizeof(float), stream);                 // denom + denom2
  hipMemsetAsync(eout, 0, (size_t)N_ENT * DIM * sizeof(float), stream);        // local acc

  k_colsum<<<1, 128, 0, stream>>>(la_w1_W, la_w1_b, la_w2_W, la_w2_b, w1s, w2s, cst);

  const int rpb = 128;
  const int gridN = (N_ENT + rpb - 1) / rpb;
  const int gridR = (N_REL + rpb - 1) / rpb;

  k_la_rows<<<gridN, 256, 0, stream>>>(ent, la_ln1_g, la_ln1_b, la_w_W, la_w_b,
                                       w1s, w2s, cst, bufA, sum1la, sum2la, N_ENT, rpb);
  k_edge<<<2048, 256, 0, stream>>>(esrc, edst, sum1la, sum2la, bufA, eout, denom, N_EDGE);
  k_la_post<<<gridN, 256, 0, stream>>>(eout, denom, la_ln2_g, la_ln2_b,
                                       ea_w1_W, ea_w1_b, sum1er, N_ENT, rpb);
  hipMemsetAsync(bufA, 0, (size_t)N_ENT * DIM * sizeof(float), stream);        // er acc2
  k_rel_dense<<<gridR, 256, 0, stream>>>(rel, ea_ln1_g, ea_ln1_b, ea_w_W, ea_w_b,
                                         dense, N_REL, rpb);
  k_rel_quad<<<gridR, 256, 0, stream>>>(rel, ea_ln1_g, ea_ln1_b, ea_w2_W, ea_w2_b,
                                        sum2er, N_REL, rpb);
  k_edge<<<2048, 256, 0, stream>>>(rsrc, rdst, sum1er, sum2er, dense, bufA, denom2, N_EDGE);
  k_final<<<gridN, 256, 0, stream>>>(bufA, denom2, eout, ea_ln2_g, ea_ln2_b,
                                     d1_W, d1_b, out, N_ENT, rpb);
}

// Round 4
// 4247.010 us; speedup vs baseline: 3.1837x; 3.1837x over previous
//
#include <hip/hip_runtime.h>
#include <math.h>

#define DIM 128
#define N_ENT 100000
#define N_REL 500
#define N_EDGE 3200000
#define LN_EPS 1e-6f
#define ALPHA 0.2f

// ---------- helpers ----------

__device__ __forceinline__ float wred(float v) {
#pragma unroll
  for (int o = 32; o > 0; o >>= 1) v += __shfl_xor(v, o, 64);
  return v;
}

// One wave computes row-vector (q) times 128x128 row-major matrix in LDS.
// Lane holds q elements (2*lane, 2*lane+1); returns output cols (2*lane, 2*lane+1).
__device__ __forceinline__ float2 wave_gemv(float q0, float q1, const float* __restrict__ Wl, int lane) {
  float ax = 0.f, ay = 0.f;
#pragma unroll
  for (int kk = 0; kk < 64; ++kk) {
    float qa = __shfl(q0, kk, 64);   // q[2kk]
    float qb = __shfl(q1, kk, 64);   // q[2kk+1]
    float2 w0 = *(const float2*)&Wl[(2 * kk) * DIM + 2 * lane];
    float2 w1 = *(const float2*)&Wl[(2 * kk + 1) * DIM + 2 * lane];
    ax = fmaf(qa, w0.x, ax); ay = fmaf(qa, w0.y, ay);
    ax = fmaf(qb, w1.x, ax); ay = fmaf(qb, w1.y, ay);
  }
  return make_float2(ax, ay);
}

__device__ __forceinline__ void stageW(float* Wl, const float* __restrict__ W) {
  for (int i = threadIdx.x; i < DIM * DIM / 4; i += blockDim.x)
    ((float4*)Wl)[i] = ((const float4*)W)[i];
  __syncthreads();
}

// LN of (x0,x1) across wave (128 elems); returns normalized pre-affine values
__device__ __forceinline__ void wave_ln(float x0, float x1, float& d0s, float& d1s) {
  float m = wred(x0 + x1) * (1.f / DIM);
  float d0 = x0 - m, d1 = x1 - m;
  float var = wred(d0 * d0 + d1 * d1) * (1.f / DIM);
  float rs = rsqrtf(var + LN_EPS);
  d0s = d0 * rs; d1s = d1 * rs;
}

// ---------- precompute: column-structure sums for local-attn sum1/sum2 ----------
// sum(q@W1+b1, axis=1) == q . rowsum_j(W1[k][j]) + sum(b1)
__global__ void k_colsum(const float* __restrict__ W1, const float* __restrict__ b1,
                         const float* __restrict__ W2, const float* __restrict__ b2,
                         float* __restrict__ w1s, float* __restrict__ w2s, float* __restrict__ cst) {
  int t = threadIdx.x;  // 128 threads
  float s1 = 0.f, s2 = 0.f;
  for (int j = 0; j < DIM; ++j) { s1 += W1[t * DIM + j]; s2 += W2[t * DIM + j]; }
  w1s[t] = s1; w2s[t] = s2;
  if (t == 0) {
    float a = 0.f, c = 0.f;
    for (int j = 0; j < DIM; ++j) { a += b1[j]; c += b2[j]; }
    cst[0] = a; cst[1] = c;
  }
}

// ---------- K1: local-attn row pass: LN -> value GEMV, sum1/sum2 dots ----------
__global__ __launch_bounds__(256) void k_la_rows(
    const float* __restrict__ ent, const float* __restrict__ g, const float* __restrict__ b,
    const float* __restrict__ W, const float* __restrict__ wb,
    const float* __restrict__ w1s, const float* __restrict__ w2s, const float* __restrict__ cst,
    float* __restrict__ value, float* __restrict__ sum1, float* __restrict__ sum2,
    int n, int rowsPerBlock) {
  __shared__ float Wl[DIM * DIM];
  stageW(Wl, W);
  int lane = threadIdx.x & 63, wid = threadIdx.x >> 6;
  float2 gv  = *(const float2*)&g[2 * lane];
  float2 bv  = *(const float2*)&b[2 * lane];
  float2 wbv = *(const float2*)&wb[2 * lane];
  float2 w1v = *(const float2*)&w1s[2 * lane];
  float2 w2v = *(const float2*)&w2s[2 * lane];
  float b1s = cst[0], b2s = cst[1];
  int r0 = blockIdx.x * rowsPerBlock;
  int r1 = min(n, r0 + rowsPerBlock);
  for (int r = r0 + wid; r < r1; r += 4) {
    float2 x = *(const float2*)&ent[(size_t)r * DIM + 2 * lane];
    float d0, d1;
    wave_ln(x.x, x.y, d0, d1);
    float q0 = fmaf(d0, gv.x, bv.x);
    float q1 = fmaf(d1, gv.y, bv.y);
    float p1 = wred(q0 * w1v.x + q1 * w1v.y);
    float p2 = wred(q0 * w2v.x + q1 * w2v.y);
    if (lane == 0) { sum1[r] = tanhf(p1 + b1s); sum2[r] = tanhf(p2 + b2s); }
    float2 acc = wave_gemv(q0, q1, Wl, lane);
    acc.x += wbv.x; acc.y += wbv.y;
    *(float2*)&value[(size_t)r * DIM + 2 * lane] = acc;
  }
}

// ---------- CSR build: histogram / scan / scatter ----------
__global__ __launch_bounds__(256) void k_hist(const int* __restrict__ src, int* __restrict__ cnt, int E) {
  int i = blockIdx.x * 256 + threadIdx.x, stride = gridDim.x * 256;
  for (; i < E; i += stride) atomicAdd(&cnt[src[i]], 1);
}

#define NSCAN 1024
__global__ __launch_bounds__(NSCAN) void k_scan(const int* __restrict__ cnt,
                                                int* __restrict__ starts,
                                                int* __restrict__ cursor, int n) {
  __shared__ int part[NSCAN];
  int t = threadIdx.x;
  int chunk = (n + NSCAN - 1) / NSCAN;
  int lo = t * chunk, hi = min(n, lo + chunk);
  int s = 0;
  for (int i = lo; i < hi; ++i) s += cnt[i];
  part[t] = s;
  __syncthreads();
  for (int off = 1; off < NSCAN; off <<= 1) {
    int other = (t >= off) ? part[t - off] : 0;
    __syncthreads();
    if (t >= off) part[t] += other;
    __syncthreads();
  }
  int run = (t == 0) ? 0 : part[t - 1];
  for (int i = lo; i < hi; ++i) {
    starts[i] = run; cursor[i] = run; run += cnt[i];
  }
}

__global__ __launch_bounds__(256) void k_scatter(const int* __restrict__ src, const int* __restrict__ dst,
                                                 int* __restrict__ cursor, int* __restrict__ sdst, int E) {
  int i = blockIdx.x * 256 + threadIdx.x, stride = gridDim.x * 256;
  for (; i < E; i += stride) {
    int pos = atomicAdd(&cursor[src[i]], 1);
    sdst[pos] = dst[i];
  }
}

// ---------- row accumulate: one wave per src row, no atomics ----------
// after k_scatter, cursor[r] == row end; starts[r] == row begin
__global__ __launch_bounds__(256) void k_accum(
    const int* __restrict__ starts, const int* __restrict__ ends,
    const int* __restrict__ sdst,
    const float* __restrict__ s1, const float* __restrict__ s2,
    const float* __restrict__ rows, float* __restrict__ outp, int n) {
  int lane = threadIdx.x & 63, wid = threadIdx.x >> 6;
  int r = blockIdx.x * 4 + wid;
  if (r >= n) return;
  int beg = starts[r], end = ends[r];
  float s1v = s1[r];
  float a0 = 0.f, a1 = 0.f, den = 0.f;
  int e = beg;
  int dNext = (e < end) ? sdst[e] : 0;
  while (e < end) {
    int d = dNext;
    ++e;
    dNext = (e < end) ? sdst[e] : 0;      // prefetch next index
    float s2v = s2[d];
    float2 v = *(const float2*)&rows[(size_t)d * DIM + 2 * lane];
    float x = s1v + s2v;
    x = x >= 0.f ? x : ALPHA * x;
    float w = __expf(x);                   // logits bounded in (-0.4, 2]: exact softmax
    a0 = fmaf(w, v.x, a0); a1 = fmaf(w, v.y, a1); den += w;
  }
  float inv = den > 0.f ? 1.f / den : 0.f;
  *(float2*)&outp[(size_t)r * DIM + 2 * lane] = make_float2(a0 * inv, a1 * inv);
}

// ---------- K3: local post: LN(ln2) in place -> e_out, er quadform sum1 ----------
__global__ __launch_bounds__(256) void k_la_post(
    float* __restrict__ buf,
    const float* __restrict__ g, const float* __restrict__ b,
    const float* __restrict__ W1, const float* __restrict__ w1b,
    float* __restrict__ sum1er, int n, int rowsPerBlock) {
  __shared__ float Wl[DIM * DIM];
  stageW(Wl, W1);
  int lane = threadIdx.x & 63, wid = threadIdx.x >> 6;
  float2 gv  = *(const float2*)&g[2 * lane];
  float2 bv  = *(const float2*)&b[2 * lane];
  float2 b1v = *(const float2*)&w1b[2 * lane];
  int r0 = blockIdx.x * rowsPerBlock, r1 = min(n, r0 + rowsPerBlock);
  for (int r = r0 + wid; r < r1; r += 4) {
    float2 a = *(const float2*)&buf[(size_t)r * DIM + 2 * lane];
    float d0, d1;
    wave_ln(a.x, a.y, d0, d1);
    float e0 = fmaf(d0, gv.x, bv.x);
    float e1 = fmaf(d1, gv.y, bv.y);
    *(float2*)&buf[(size_t)r * DIM + 2 * lane] = make_float2(e0, e1);
    // sum1_er = tanh(e^T W1 e + b1 . e)
    float2 y = wave_gemv(e0, e1, Wl, lane);
    float p = wred(y.x * e0 + y.y * e1 + b1v.x * e0 + b1v.y * e1);
    if (lane == 0) sum1er[r] = tanhf(p);
  }
}

// ---------- K4a: rel rows: LN(ea_ln1) -> dense GEMV ----------
__global__ __launch_bounds__(256) void k_rel_dense(
    const float* __restrict__ rel, const float* __restrict__ g, const float* __restrict__ b,
    const float* __restrict__ W, const float* __restrict__ wb,
    float* __restrict__ dense, int n, int rowsPerBlock) {
  __shared__ float Wl[DIM * DIM];
  stageW(Wl, W);
  int lane = threadIdx.x & 63, wid = threadIdx.x >> 6;
  float2 gv  = *(const float2*)&g[2 * lane];
  float2 bv  = *(const float2*)&b[2 * lane];
  float2 wbv = *(const float2*)&wb[2 * lane];
  int r0 = blockIdx.x * rowsPerBlock, r1 = min(n, r0 + rowsPerBlock);
  for (int r = r0 + wid; r < r1; r += 4) {
    float2 x = *(const float2*)&rel[(size_t)r * DIM + 2 * lane];
    float d0, d1;
    wave_ln(x.x, x.y, d0, d1);
    float e0 = fmaf(d0, gv.x, bv.x);
    float e1 = fmaf(d1, gv.y, bv.y);
    float2 acc = wave_gemv(e0, e1, Wl, lane);
    acc.x += wbv.x; acc.y += wbv.y;
    *(float2*)&dense[(size_t)r * DIM + 2 * lane] = acc;
  }
}

// ---------- K4b: rel rows: LN(ea_ln1) -> quadform sum2_er ----------
__global__ __launch_bounds__(256) void k_rel_quad(
    const float* __restrict__ rel, const float* __restrict__ g, const float* __restrict__ b,
    const float* __restrict__ W2, const float* __restrict__ w2b,
    float* __restrict__ sum2er, int n, int rowsPerBlock) {
  __shared__ float Wl[DIM * DIM];
  stageW(Wl, W2);
  int lane = threadIdx.x & 63, wid = threadIdx.x >> 6;
  float2 gv  = *(const float2*)&g[2 * lane];
  float2 bv  = *(const float2*)&b[2 * lane];
  float2 b2v = *(const float2*)&w2b[2 * lane];
  int r0 = blockIdx.x * rowsPerBlock, r1 = min(n, r0 + rowsPerBlock);
  for (int r = r0 + wid; r < r1; r += 4) {
    float2 x = *(const float2*)&rel[(size_t)r * DIM + 2 * lane];
    float d0, d1;
    wave_ln(x.x, x.y, d0, d1);
    float e0 = fmaf(d0, gv.x, bv.x);
    float e1 = fmaf(d1, gv.y, bv.y);
    float2 y = wave_gemv(e0, e1, Wl, lane);
    float p = wred(y.x * e0 + y.y * e1 + b2v.x * e0 + b2v.y * e1);
    if (lane == 0) sum2er[r] = tanhf(p);
  }
}

// ---------- K6: final: er LN, d1 GEMV, combine with e_out ----------
// acc2 aliases out (in-place safe: each thread reads its element before writing it)
__global__ __launch_bounds__(256) void k_final(
    const float* acc2, const float* __restrict__ eout,
    const float* __restrict__ g, const float* __restrict__ b,
    const float* __restrict__ d1W, const float* __restrict__ d1b,
    float* out, int n, int rowsPerBlock) {
  __shared__ float Wl[DIM * DIM];
  stageW(Wl, d1W);
  int lane = threadIdx.x & 63, wid = threadIdx.x >> 6;
  float2 gv  = *(const float2*)&g[2 * lane];
  float2 bv  = *(const float2*)&b[2 * lane];
  float2 dbv = *(const float2*)&d1b[2 * lane];
  int r0 = blockIdx.x * rowsPerBlock, r1 = min(n, r0 + rowsPerBlock);
  for (int r = r0 + wid; r < r1; r += 4) {
    float2 a = *(const float2*)&acc2[(size_t)r * DIM + 2 * lane];
    float d0, d1;
    wave_ln(a.x, a.y, d0, d1);
    float er0 = fmaf(d0, gv.x, bv.x);
    float er1 = fmaf(d1, gv.y, bv.y);
    float2 y = wave_gemv(er0, er1, Wl, lane);
    float2 e = *(const float2*)&eout[(size_t)r * DIM + 2 * lane];
    float2 o;
    o.x = e.x + 0.6f * (y.x + dbv.x);
    o.y = e.y + 0.6f * (y.y + dbv.y);
    *(float2*)&out[(size_t)r * DIM + 2 * lane] = o;
  }
}

extern "C" void kernel_launch(void* const* d_in, const int* in_sizes, int n_in,
                              void* d_out, int out_size, void* d_ws, size_t ws_size,
                              hipStream_t stream) {
  const float* ent      = (const float*)d_in[0];
  const float* rel      = (const float*)d_in[1];
  const int*   esrc     = (const int*)d_in[2];
  const int*   edst     = (const int*)d_in[3];
  const int*   rsrc     = (const int*)d_in[4];
  const int*   rdst     = (const int*)d_in[5];
  const float* la_ln1_g = (const float*)d_in[6];
  const float* la_ln1_b = (const float*)d_in[7];
  const float* la_w_W   = (const float*)d_in[8];
  const float* la_w_b   = (const float*)d_in[9];
  const float* la_w1_W  = (const float*)d_in[10];
  const float* la_w1_b  = (const float*)d_in[11];
  const float* la_w2_W  = (const float*)d_in[12];
  const float* la_w2_b  = (const float*)d_in[13];
  const float* la_ln2_g = (const float*)d_in[14];
  const float* la_ln2_b = (const float*)d_in[15];
  const float* ea_ln1_g = (const float*)d_in[16];
  const float* ea_ln1_b = (const float*)d_in[17];
  const float* ea_w_W   = (const float*)d_in[18];
  const float* ea_w_b   = (const float*)d_in[19];
  const float* ea_w1_W  = (const float*)d_in[20];
  const float* ea_w1_b  = (const float*)d_in[21];
  const float* ea_w2_W  = (const float*)d_in[22];
  const float* ea_w2_b  = (const float*)d_in[23];
  const float* ea_ln2_g = (const float*)d_in[24];
  const float* ea_ln2_b = (const float*)d_in[25];
  const float* d1_W     = (const float*)d_in[26];
  const float* d1_b     = (const float*)d_in[27];
  float* out = (float*)d_out;

  // ws layout: ~16.67M slots (~66.7 MB)
  float* f      = (float*)d_ws;
  float* bufA   = f;                        // local numerator -> e_out (after LN)
  int*   sdst   = (int*)(f + 12800000);     // [E] sorted dst (reused for er)
  int*   cnt    = (int*)(f + 16000000);     // [N]
  int*   starts = (int*)(f + 16100000);     // [N]
  int*   cursor = (int*)(f + 16200000);     // [N] (becomes row-ends after scatter)
  float* sum1la = f + 16300000;             // [N]
  float* sum2la = f + 16400000;             // [N]
  float* sum1er = f + 16500000;             // [N]
  float* sum2er = f + 16600000;             // [R]
  float* dense  = f + 16600512;             // [R*128]
  float* w1s    = f + 16664512;             // [128]
  float* w2s    = f + 16664640;             // [128]
  float* cst    = f + 16664768;             // [2]
  float* value  = out;                      // [N*128] value lives in d_out during local phase

  const int rpb = 128;
  const int gridN = (N_ENT + rpb - 1) / rpb;
  const int gridR = (N_REL + rpb - 1) / rpb;
  const int gridA = (N_ENT + 3) / 4;        // 4 rows (waves) per block

  k_colsum<<<1, 128, 0, stream>>>(la_w1_W, la_w1_b, la_w2_W, la_w2_b, w1s, w2s, cst);
  k_la_rows<<<gridN, 256, 0, stream>>>(ent, la_ln1_g, la_ln1_b, la_w_W, la_w_b,
                                       w1s, w2s, cst, value, sum1la, sum2la, N_ENT, rpb);

  // ---- local phase CSR + accumulate (no atomics on the 51MB accumulator) ----
  hipMemsetAsync(cnt, 0, N_ENT * sizeof(int), stream);
  k_hist<<<2048, 256, 0, stream>>>(esrc, cnt, N_EDGE);
  k_scan<<<1, NSCAN, 0, stream>>>(cnt, starts, cursor, N_ENT);
  k_scatter<<<2048, 256, 0, stream>>>(esrc, edst, cursor, sdst, N_EDGE);
  k_accum<<<gridA, 256, 0, stream>>>(starts, cursor, sdst, sum1la, sum2la,
                                     value, bufA, N_ENT);
  k_la_post<<<gridN, 256, 0, stream>>>(bufA, la_ln2_g, la_ln2_b,
                                       ea_w1_W, ea_w1_b, sum1er, N_ENT, rpb);

  // ---- er phase ----
  k_rel_dense<<<gridR, 256, 0, stream>>>(rel, ea_ln1_g, ea_ln1_b, ea_w_W, ea_w_b,
                                         dense, N_REL, rpb);
  k_rel_quad<<<gridR, 256, 0, stream>>>(rel, ea_ln1_g, ea_ln1_b, ea_w2_W, ea_w2_b,
                                        sum2er, N_REL, rpb);
  hipMemsetAsync(cnt, 0, N_ENT * sizeof(int), stream);
  k_hist<<<2048, 256, 0, stream>>>(rsrc, cnt, N_EDGE);
  k_scan<<<1, NSCAN, 0, stream>>>(cnt, starts, cursor, N_ENT);
  k_scatter<<<2048, 256, 0, stream>>>(rsrc, rdst, cursor, sdst, N_EDGE);
  k_accum<<<gridA, 256, 0, stream>>>(starts, cursor, sdst, sum1er, sum2er,
                                     dense, out, N_ENT);   // er numerator -> d_out (value dead)

  k_final<<<gridN, 256, 0, stream>>>(out, bufA, ea_ln2_g, ea_ln2_b,
                                     d1_W, d1_b, out, N_ENT, rpb);
}